// Round 1
// baseline (1701.069 us; speedup 1.0000x reference)
//
#include <hip/hip_runtime.h>
#include <cmath>

#define LSEQ 2048
#define DM   1024
#define TILE 64
#define KT   16
#define NT   (LSEQ / TILE)   // 32 row/col tiles

// log2(0.96875)
#define LOG2_GAMMA (-0.04580369f)
// log2(10000)
#define LOG2_1E4 (13.28771238f)

// ---------------------------------------------------------------------------
// Kernel 1: Y = X @ W  (M=LSEQ rows of one batch, N=DM, K=DM)
// mode 0 = Q (xpos), 1 = K (xpos downscale), 2 = V (plain)
// ---------------------------------------------------------------------------
__global__ __launch_bounds__(256) void qkv_xpos_kernel(
    const float* __restrict__ X,
    const float* __restrict__ Wq, const float* __restrict__ Wk,
    const float* __restrict__ Wv,
    float* __restrict__ Qo, float* __restrict__ Ko, float* __restrict__ Vo)
{
    const int mode = blockIdx.z;
    const float* __restrict__ W = (mode == 0) ? Wq : (mode == 1) ? Wk : Wv;
    float* __restrict__ O       = (mode == 0) ? Qo : (mode == 1) ? Ko : Vo;

    const int n0 = blockIdx.y * TILE;   // row (sequence position l)
    const int c0 = blockIdx.x * TILE;   // col
    const int tx = threadIdx.x, ty = threadIdx.y;   // 16 x 16
    const int tid = ty * 16 + tx;

    __shared__ float As[KT][TILE + 4];  // [k][row], padded for float4 reads
    __shared__ float Bs[KT][TILE];      // [k][col]

    float acc[4][4] = {};

    for (int k0 = 0; k0 < DM; k0 += KT) {
        #pragma unroll
        for (int t = 0; t < 4; ++t) {
            int e = tid + t * 256;
            int r = e >> 4, kk = e & 15;
            As[kk][r] = X[(size_t)(n0 + r) * DM + k0 + kk];
        }
        #pragma unroll
        for (int t = 0; t < 4; ++t) {
            int e = tid + t * 256;
            int kk = e >> 6, c = e & 63;
            Bs[kk][c] = W[(size_t)(k0 + kk) * DM + c0 + c];
        }
        __syncthreads();
        #pragma unroll
        for (int kk = 0; kk < KT; ++kk) {
            float4 av = *(const float4*)&As[kk][ty * 4];
            float4 bv = *(const float4*)&Bs[kk][tx * 4];
            float a[4] = {av.x, av.y, av.z, av.w};
            float b[4] = {bv.x, bv.y, bv.z, bv.w};
            #pragma unroll
            for (int i = 0; i < 4; ++i)
                #pragma unroll
                for (int j = 0; j < 4; ++j)
                    acc[i][j] += a[i] * b[j];
        }
        __syncthreads();
    }

    if (mode == 2) {
        #pragma unroll
        for (int i = 0; i < 4; ++i) {
            int row = n0 + ty * 4 + i;
            float4 v = make_float4(acc[i][0], acc[i][1], acc[i][2], acc[i][3]);
            *(float4*)&O[(size_t)row * DM + c0 + tx * 4] = v;
        }
    } else {
        const float sgn = (mode == 0) ? 1.0f : -1.0f;   // downscale for K
        #pragma unroll
        for (int i = 0; i < 4; ++i) {
            int l = n0 + ty * 4 + i;
            float lf = (float)l;
            #pragma unroll
            for (int j = 0; j < 4; j += 2) {
                int c = c0 + tx * 4 + j;
                int p = c >> 1;                         // pair index, 0..511
                // scale_vec[p] = (2p + 0.4*1024) / (1.4*1024)
                float sv = (2.0f * (float)p + 409.6f) * (1.0f / 1433.6f);
                float scale = exp2f(sgn * lf * (1.0f / 512.0f) * log2f(sv));
                // inv_freq[p] = 10000^(-p/512)
                float invf = exp2f(-(float)p * (LOG2_1E4 / 512.0f));
                float sinu = lf * invf;
                float s, cth;
                sincosf(sinu, &s, &cth);
                s *= scale; cth *= scale;
                float y0 = acc[i][j], y1 = acc[i][j + 1];
                acc[i][j]     = y0 * cth - y1 * s;
                acc[i][j + 1] = y1 * cth + y0 * s;
            }
            float4 v = make_float4(acc[i][0], acc[i][1], acc[i][2], acc[i][3]);
            *(float4*)&O[(size_t)l * DM + c0 + tx * 4] = v;
        }
    }
}

// ---------------------------------------------------------------------------
// Kernel 2: S[n,m] = (Q[n] . K[m]) * gamma^(n-m) for n >= m else 0
// Only lower-triangular 64x64 tiles are computed; upper tiles never read.
// ---------------------------------------------------------------------------
__global__ __launch_bounds__(256) void score_kernel(
    const float* __restrict__ Q, const float* __restrict__ Km,
    float* __restrict__ S)
{
    const int bi = blockIdx.y, bj = blockIdx.x;
    if (bj > bi) return;   // strictly upper tiles: never read downstream
    const int n0 = bi * TILE, m0 = bj * TILE;
    const int tx = threadIdx.x, ty = threadIdx.y;
    const int tid = ty * 16 + tx;

    __shared__ float As[KT][TILE + 4];   // Q  [k][n]
    __shared__ float Bs[KT][TILE + 4];   // K  [k][m]

    float acc[4][4] = {};

    for (int k0 = 0; k0 < DM; k0 += KT) {
        #pragma unroll
        for (int t = 0; t < 4; ++t) {
            int e = tid + t * 256;
            int r = e >> 4, kk = e & 15;
            As[kk][r] = Q[(size_t)(n0 + r) * DM + k0 + kk];
            Bs[kk][r] = Km[(size_t)(m0 + r) * DM + k0 + kk];
        }
        __syncthreads();
        #pragma unroll
        for (int kk = 0; kk < KT; ++kk) {
            float4 av = *(const float4*)&As[kk][ty * 4];
            float4 bv = *(const float4*)&Bs[kk][tx * 4];
            float a[4] = {av.x, av.y, av.z, av.w};
            float b[4] = {bv.x, bv.y, bv.z, bv.w};
            #pragma unroll
            for (int i = 0; i < 4; ++i)
                #pragma unroll
                for (int j = 0; j < 4; ++j)
                    acc[i][j] += a[i] * b[j];
        }
        __syncthreads();
    }

    #pragma unroll
    for (int i = 0; i < 4; ++i) {
        int n = n0 + ty * 4 + i;
        #pragma unroll
        for (int j = 0; j < 4; ++j) {
            int m = m0 + tx * 4 + j;
            int diff = n - m;
            float d = (diff >= 0) ? exp2f((float)diff * LOG2_GAMMA) : 0.0f;
            acc[i][j] *= d;
        }
        float4 v = make_float4(acc[i][0], acc[i][1], acc[i][2], acc[i][3]);
        *(float4*)&S[(size_t)n * LSEQ + m0 + tx * 4] = v;
    }
}

// ---------------------------------------------------------------------------
// Kernel 3: O = S @ V with k bounded by row tile (triangular skip)
// ---------------------------------------------------------------------------
__global__ __launch_bounds__(256) void av_kernel(
    const float* __restrict__ S, const float* __restrict__ V,
    float* __restrict__ O)
{
    const int n0 = blockIdx.y * TILE, c0 = blockIdx.x * TILE;
    const int tx = threadIdx.x, ty = threadIdx.y;
    const int tid = ty * 16 + tx;
    const int kmax = n0 + TILE;   // S is zero (and unwritten) for m >= n0+64

    __shared__ float As[KT][TILE + 4];   // S tile [k=m][n]
    __shared__ float Bs[KT][TILE];       // V tile [k=m][c]

    float acc[4][4] = {};

    for (int k0 = 0; k0 < kmax; k0 += KT) {
        #pragma unroll
        for (int t = 0; t < 4; ++t) {
            int e = tid + t * 256;
            int r = e >> 4, kk = e & 15;
            As[kk][r] = S[(size_t)(n0 + r) * LSEQ + k0 + kk];
        }
        #pragma unroll
        for (int t = 0; t < 4; ++t) {
            int e = tid + t * 256;
            int kk = e >> 6, c = e & 63;
            Bs[kk][c] = V[(size_t)(k0 + kk) * DM + c0 + c];
        }
        __syncthreads();
        #pragma unroll
        for (int kk = 0; kk < KT; ++kk) {
            float4 av = *(const float4*)&As[kk][ty * 4];
            float4 bv = *(const float4*)&Bs[kk][tx * 4];
            float a[4] = {av.x, av.y, av.z, av.w};
            float b[4] = {bv.x, bv.y, bv.z, bv.w};
            #pragma unroll
            for (int i = 0; i < 4; ++i)
                #pragma unroll
                for (int j = 0; j < 4; ++j)
                    acc[i][j] += a[i] * b[j];
        }
        __syncthreads();
    }

    #pragma unroll
    for (int i = 0; i < 4; ++i) {
        int row = n0 + ty * 4 + i;
        float4 v = make_float4(acc[i][0], acc[i][1], acc[i][2], acc[i][3]);
        *(float4*)&O[(size_t)row * DM + c0 + tx * 4] = v;
    }
}

// ---------------------------------------------------------------------------
extern "C" void kernel_launch(void* const* d_in, const int* in_sizes, int n_in,
                              void* d_out, int out_size, void* d_ws, size_t ws_size,
                              hipStream_t stream)
{
    const float* X  = (const float*)d_in[0];
    const float* Wq = (const float*)d_in[1];
    const float* Wk = (const float*)d_in[2];
    const float* Wv = (const float*)d_in[3];
    float* out = (float*)d_out;
    float* ws  = (float*)d_ws;

    const int B = 4;
    const size_t LH = (size_t)LSEQ * DM;    // 2M floats

    float* Q = ws;
    float* K = ws + LH;
    float* V = ws + 2 * LH;
    float* S = ws + 3 * LH;   // LSEQ*LSEQ floats; total ws use ~42 MB

    dim3 blk(16, 16);
    for (int b = 0; b < B; ++b) {
        const float* Xb = X + (size_t)b * LH;
        qkv_xpos_kernel<<<dim3(DM / TILE, LSEQ / TILE, 3), blk, 0, stream>>>(
            Xb, Wq, Wk, Wv, Q, K, V);
        score_kernel<<<dim3(NT, NT), blk, 0, stream>>>(Q, K, S);
        av_kernel<<<dim3(DM / TILE, LSEQ / TILE), blk, 0, stream>>>(
            S, V, out + (size_t)b * LH);
    }
}

// Round 2
// 287.816 us; speedup vs baseline: 5.9103x; 5.9103x over previous
//
#include <hip/hip_runtime.h>

typedef __attribute__((ext_vector_type(8))) short short8;
typedef __attribute__((ext_vector_type(4))) short short4v;
typedef __attribute__((ext_vector_type(4))) float floatx4;
typedef unsigned short ushort_t;

#define LSEQ   2048
#define DMODEL 1024
#define BM 128
#define BN 128
#define BKT 32

// log2(0.96875)
#define L2GAMMA (-0.045803595f)
// log2(10000)/512
#define L2E4_512 (0.0259525632f)

// float -> bf16 with round-to-nearest-even
__device__ __forceinline__ ushort_t f2b(float x) {
    union { float f; unsigned u; } v; v.f = x;
    unsigned r = v.u + 0x7fffu + ((v.u >> 16) & 1u);
    return (ushort_t)(r >> 16);
}

// async global->LDS, 16B per lane. LDS dest is wave-uniform base + lane*16;
// our layouts are lane-contiguous by construction (no padding).
#define GLOAD_LDS16(gptr, lptr)                                                     \
    __builtin_amdgcn_global_load_lds(                                               \
        (const __attribute__((address_space(1))) unsigned int*)(gptr),              \
        (__attribute__((address_space(3))) unsigned int*)(lptr), 16, 0, 0)

// ---------------------------------------------------------------------------
// Shared GEMM core: C(128x128) += A[aRow0..][k] * B[bRow0..][k]^T, bf16 MFMA.
// A,B both K-contiguous (ldX in elements). kDepth multiple of 32.
// ---------------------------------------------------------------------------
__device__ __forceinline__ void gemm_core(
    const ushort_t* __restrict__ Ag, int lda, int aRow0,
    const ushort_t* __restrict__ Bg, int ldb, int bRow0,
    int kDepth, ushort_t* As, ushort_t* Bs, floatx4 acc[4][4])
{
    const int tid  = threadIdx.x;
    const int wave = tid >> 6, lane = tid & 63;
    const int wm = wave >> 1, wn = wave & 1;
    const int l15 = lane & 15, quad = lane >> 4;
    const int srow = wave * 16 + (lane >> 2);   // 0..79 (per-wave 16-row chunk)
    const int skof = (lane & 3) * 8;            // k-offset in elements

    for (int k0 = 0; k0 < kDepth; k0 += BKT) {
        __syncthreads();  // previous iter's ds_reads done before overwrite
        GLOAD_LDS16(Ag + (size_t)(aRow0 + srow) * lda + k0 + skof,
                    As + srow * BKT + skof);
        GLOAD_LDS16(Ag + (size_t)(aRow0 + 64 + srow) * lda + k0 + skof,
                    As + (64 + srow) * BKT + skof);
        GLOAD_LDS16(Bg + (size_t)(bRow0 + srow) * ldb + k0 + skof,
                    Bs + srow * BKT + skof);
        GLOAD_LDS16(Bg + (size_t)(bRow0 + 64 + srow) * ldb + k0 + skof,
                    Bs + (64 + srow) * BKT + skof);
        __syncthreads();  // drains vmcnt (global_load_lds) + barrier

        short8 af[4], bf[4];
        #pragma unroll
        for (int i = 0; i < 4; ++i) {
            af[i] = *(const short8*)(As + (wm * 64 + i * 16 + l15) * BKT + quad * 8);
            bf[i] = *(const short8*)(Bs + (wn * 64 + i * 16 + l15) * BKT + quad * 8);
        }
        #pragma unroll
        for (int i = 0; i < 4; ++i)
            #pragma unroll
            for (int j = 0; j < 4; ++j)
                acc[i][j] = __builtin_amdgcn_mfma_f32_16x16x32_bf16(
                    af[i], bf[j], acc[i][j], 0, 0, 0);
    }
}

// ---------------------------------------------------------------------------
// Prep: fp32 -> bf16 cast of X
// ---------------------------------------------------------------------------
__global__ __launch_bounds__(256) void cast_x_kernel(
    const float4* __restrict__ X, short4v* __restrict__ Xb, int n4)
{
    int i = blockIdx.x * 256 + threadIdx.x;
    if (i < n4) {
        float4 v = X[i];
        short4v o;
        o.x = (short)f2b(v.x); o.y = (short)f2b(v.y);
        o.z = (short)f2b(v.z); o.w = (short)f2b(v.w);
        Xb[i] = o;
    }
}

// ---------------------------------------------------------------------------
// Prep: W (fp32 [K][N]) -> Wt (bf16 [N][K]) for all three weights
// ---------------------------------------------------------------------------
__global__ __launch_bounds__(256) void wtrans_kernel(
    const float* __restrict__ Wq, const float* __restrict__ Wk,
    const float* __restrict__ Wv, ushort_t* __restrict__ Wt)
{
    const float* W = blockIdx.z == 0 ? Wq : blockIdx.z == 1 ? Wk : Wv;
    ushort_t* O = Wt + (size_t)blockIdx.z * (DMODEL * DMODEL);
    __shared__ float t[32][33];
    const int x = threadIdx.x & 31, y = (threadIdx.x >> 5) * 4;
    const int k0 = blockIdx.y * 32, n0 = blockIdx.x * 32;
    #pragma unroll
    for (int j = 0; j < 4; ++j)
        t[y + j][x] = W[(size_t)(k0 + y + j) * DMODEL + n0 + x];
    __syncthreads();
    #pragma unroll
    for (int j = 0; j < 4; ++j)
        O[(size_t)(n0 + y + j) * DMODEL + k0 + x] = f2b(t[x][y + j]);
}

// ---------------------------------------------------------------------------
// Stage 1: Q/K/V = Xb @ W, xpos epilogue for Q (z=0), K (z=1, downscale),
// transposed bf16 store for V (z=2).
// ---------------------------------------------------------------------------
__global__ __launch_bounds__(256) void qkv_kernel(
    const ushort_t* __restrict__ Xb, const ushort_t* __restrict__ Wt,
    ushort_t* __restrict__ Q, ushort_t* __restrict__ Ko, ushort_t* __restrict__ Vt)
{
    __shared__ ushort_t As[BM * BKT], Bs[BN * BKT];
    const int mode = blockIdx.z;
    floatx4 acc[4][4] = {};
    gemm_core(Xb, DMODEL, blockIdx.y * BM,
              Wt + (size_t)mode * (DMODEL * DMODEL), DMODEL, blockIdx.x * BN,
              DMODEL, As, Bs, acc);

    const int wave = threadIdx.x >> 6, lane = threadIdx.x & 63;
    const int wm = wave >> 1, wn = wave & 1;
    const int l15 = lane & 15, quad = lane >> 4;
    const int rBase = blockIdx.y * BM + wm * 64 + quad * 4;  // + mi*16 + j
    const int cBase = blockIdx.x * BN + wn * 64 + l15;       // + ni*16

    if (mode == 2) {
        // V: store transposed Vt[b][col][lpos], 4 consecutive rows per lane
        #pragma unroll
        for (int mi = 0; mi < 4; ++mi) {
            int row = rBase + mi * 16;
            int b = row >> 11, lpos = row & 2047;
            #pragma unroll
            for (int ni = 0; ni < 4; ++ni) {
                int col = cBase + ni * 16;
                short4v pk;
                pk.x = (short)f2b(acc[mi][ni].x);
                pk.y = (short)f2b(acc[mi][ni].y);
                pk.z = (short)f2b(acc[mi][ni].z);
                pk.w = (short)f2b(acc[mi][ni].w);
                *(short4v*)(Vt + (size_t)b * (LSEQ * DMODEL)
                               + (size_t)col * LSEQ + lpos) = pk;
            }
        }
    } else {
        const float sgn = (mode == 0) ? 1.0f : -1.0f;
        ushort_t* O = (mode == 0) ? Q : Ko;
        #pragma unroll
        for (int ni = 0; ni < 4; ++ni) {
            int col = cBase + ni * 16;
            int p = col >> 1;  // same p for the even/odd lane pair
            float sv   = (2.0f * (float)p + 409.6f) * (1.0f / 1433.6f);
            float l2sv = __log2f(sv) * (sgn / 512.0f);
            float invf = exp2f(-(float)p * L2E4_512);
            #pragma unroll
            for (int mi = 0; mi < 4; ++mi) {
                #pragma unroll
                for (int j = 0; j < 4; ++j) {
                    int row = rBase + mi * 16 + j;
                    float lf = (float)(row & 2047);
                    float scale = exp2f(lf * l2sv);
                    float s, c;
                    __sincosf(lf * invf, &s, &c);
                    s *= scale; c *= scale;
                    float v  = acc[mi][ni][j];
                    float pv = __shfl_xor(v, 1);
                    float res = (lane & 1) ? (v * c + pv * s) : (v * c - pv * s);
                    O[(size_t)row * DMODEL + col] = f2b(res);
                }
            }
        }
    }
}

// ---------------------------------------------------------------------------
// Stage 2: S = (Q . K^T) * gamma^(n-m) [n>=m], lower-triangle tiles only
// ---------------------------------------------------------------------------
__global__ __launch_bounds__(256) void score_kernel(
    const ushort_t* __restrict__ Q, const ushort_t* __restrict__ Kc,
    ushort_t* __restrict__ S)
{
    const int bj = blockIdx.x, bi = blockIdx.y, z = blockIdx.z;
    if (bj > bi) return;  // upper tiles never read downstream
    __shared__ ushort_t As[BM * BKT], Bs[BN * BKT];
    floatx4 acc[4][4] = {};
    const size_t zoff = (size_t)z * (LSEQ * DMODEL);
    gemm_core(Q + zoff, DMODEL, bi * BM, Kc + zoff, DMODEL, bj * BN,
              DMODEL, As, Bs, acc);

    const int wave = threadIdx.x >> 6, lane = threadIdx.x & 63;
    const int wm = wave >> 1, wn = wave & 1;
    const int l15 = lane & 15, quad = lane >> 4;
    const int nBase = bi * BM + wm * 64 + quad * 4;
    const int mBase = bj * BN + wn * 64 + l15;
    ushort_t* Sz = S + (size_t)z * LSEQ * LSEQ;
    #pragma unroll
    for (int mi = 0; mi < 4; ++mi)
        #pragma unroll
        for (int ni = 0; ni < 4; ++ni) {
            int m = mBase + ni * 16;
            #pragma unroll
            for (int j = 0; j < 4; ++j) {
                int n = nBase + mi * 16 + j;
                int diff = n - m;
                float d = (diff >= 0) ? exp2f((float)diff * L2GAMMA) : 0.0f;
                Sz[(size_t)n * LSEQ + m] = f2b(acc[mi][ni][j] * d);
            }
        }
}

// ---------------------------------------------------------------------------
// Stage 3: O = S @ V via S[n][m] * Vt[c][m], k bounded by row tile
// ---------------------------------------------------------------------------
__global__ __launch_bounds__(256) void av_kernel(
    const ushort_t* __restrict__ S, const ushort_t* __restrict__ Vt,
    float* __restrict__ Out)
{
    const int bx = blockIdx.x, bi = blockIdx.y, z = blockIdx.z;
    __shared__ ushort_t As[BM * BKT], Bs[BN * BKT];
    floatx4 acc[4][4] = {};
    gemm_core(S + (size_t)z * LSEQ * LSEQ, LSEQ, bi * BM,
              Vt + (size_t)z * (LSEQ * DMODEL), LSEQ, bx * BN,
              (bi + 1) * BM, As, Bs, acc);

    const int wave = threadIdx.x >> 6, lane = threadIdx.x & 63;
    const int wm = wave >> 1, wn = wave & 1;
    const int l15 = lane & 15, quad = lane >> 4;
    const int rBase = bi * BM + wm * 64 + quad * 4;
    const int cBase = bx * BN + wn * 64 + l15;
    float* Oz = Out + (size_t)z * (LSEQ * DMODEL);
    #pragma unroll
    for (int mi = 0; mi < 4; ++mi)
        #pragma unroll
        for (int ni = 0; ni < 4; ++ni)
            #pragma unroll
            for (int j = 0; j < 4; ++j)
                Oz[(size_t)(rBase + mi * 16 + j) * DMODEL + cBase + ni * 16] =
                    acc[mi][ni][j];
}

// ---------------------------------------------------------------------------
extern "C" void kernel_launch(void* const* d_in, const int* in_sizes, int n_in,
                              void* d_out, int out_size, void* d_ws, size_t ws_size,
                              hipStream_t stream)
{
    const float* X  = (const float*)d_in[0];
    const float* Wq = (const float*)d_in[1];
    const float* Wk = (const float*)d_in[2];
    const float* Wv = (const float*)d_in[3];
    float* out = (float*)d_out;
    ushort_t* ws16 = (ushort_t*)d_ws;

    const size_t LH  = (size_t)LSEQ * DMODEL;     // 2,097,152 elems / batch
    const size_t WSZ = (size_t)DMODEL * DMODEL;   // 1,048,576 elems / weight
    const size_t SSZ = (size_t)LSEQ * LSEQ;       // 4,194,304 elems / batch

    // workspace need: Wt(3*WSZ) + bs*(Xb+Q+K+Vt = 4*LH) + bs*S, in bf16
    size_t need4 = 2 * (3 * WSZ + 4 * (4 * LH + SSZ));   // ~102 MB
    const int bs = (ws_size >= need4) ? 4 : 1;           // fallback: ~31 MB

    ushort_t* Wt = ws16;
    ushort_t* Xb = Wt + 3 * WSZ;
    ushort_t* Q  = Xb + (size_t)bs * LH;
    ushort_t* Kb = Q  + (size_t)bs * LH;
    ushort_t* Vt = Kb + (size_t)bs * LH;
    ushort_t* S  = Vt + (size_t)bs * LH;

    wtrans_kernel<<<dim3(32, 32, 3), 256, 0, stream>>>(Wq, Wk, Wv, Wt);

    for (int p = 0; p < 4 / bs; ++p) {
        const float* Xp = X + (size_t)p * bs * LH;
        cast_x_kernel<<<dim3(bs * 2048), 256, 0, stream>>>(
            (const float4*)Xp, (short4v*)Xb, bs * (int)(LH / 4));
        qkv_kernel<<<dim3(8, bs * 16, 3), 256, 0, stream>>>(Xb, Wt, Q, Kb, Vt);
        score_kernel<<<dim3(16, 16, bs), 256, 0, stream>>>(Q, Kb, S);
        av_kernel<<<dim3(8, 16, bs), 256, 0, stream>>>(S, Vt,
            out + (size_t)p * bs * LH);
    }
}